// Round 4
// baseline (519.844 us; speedup 1.0000x reference)
//
#include <hip/hip_runtime.h>
#include <cstdint>

typedef unsigned short u16;
typedef unsigned long long u64;
typedef __attribute__((ext_vector_type(8))) short bf16x8;
typedef __attribute__((ext_vector_type(4))) float f32x4;

__device__ __forceinline__ u16 f2b(float f){
  union { float f; uint32_t i; } v; v.f = f;
  uint32_t r = v.i + 0x7FFFu + ((v.i >> 16) & 1u);   // RNE
  return (u16)(r >> 16);
}
__device__ __forceinline__ float b2f(u16 u){
  union { uint32_t i; float f; } v; v.i = ((uint32_t)u) << 16; return v.f;
}
__device__ __forceinline__ float sigmoidf(float x){ return 1.0f / (1.0f + __expf(-x)); }
__device__ __forceinline__ uint32_t nzb(float a){            // bf16 1.0 if a!=0
  return (__float_as_uint(a) << 1) ? 0x3F80u : 0u;
}

// ---------------------------------------------------------------- K1: ghat[b,h]
__global__ void k_pre(const float* __restrict__ nh, const float* __restrict__ Wg,
                      const float* __restrict__ bg, float* __restrict__ ghat){
  int b = threadIdx.x >> 6, h = threadIdx.x & 63;
  float g = bg[h];
  for (int d = 0; d < 64; ++d) g += nh[b*64 + d] * Wg[d*64 + h];
  float ss = g * g;
  #pragma unroll
  for (int o = 32; o > 0; o >>= 1) ss += __shfl_xor(ss, o, 64);
  ghat[b*64 + h] = g / (sqrtf(ss) + 1e-30f);
}

// ------------------------------------------- K2: Xk = all_w@Wwk+bwk, Xs = all_w@Wws+bws
__global__ __launch_bounds__(256) void k_xform(
    const float* __restrict__ w0, const float* __restrict__ w1,
    const float* __restrict__ Wwk, const float* __restrict__ bwk,
    const float* __restrict__ Wws, const float* __restrict__ bws,
    float* __restrict__ Xk, float* __restrict__ Xs){
  __shared__ float sWk[4096], sWs[4096];
  int tid = threadIdx.x;
  for (int i = tid; i < 1024; i += 256){
    ((float4*)sWk)[i] = ((const float4*)Wwk)[i];
    ((float4*)sWs)[i] = ((const float4*)Wws)[i];
  }
  __syncthreads();
  int lane = tid & 63, wave = tid >> 6;
  float bk = bwk[lane], bs = bws[lane];
  float aw[4];
  #pragma unroll
  for (int t = 0; t < 4; ++t){
    int row = blockIdx.x*4 + wave + t*2048;
    int b = row >> 12, n = row & 4095;
    aw[t] = (n < 2048) ? w0[((size_t)(b*2048 + n))*64 + lane]
                       : w1[((size_t)(b*2048 + n - 2048))*64 + lane];
  }
  #pragma unroll
  for (int t = 0; t < 4; ++t){
    int row = blockIdx.x*4 + wave + t*2048;
    float xk = bk, xs = bs;
    #pragma unroll 8
    for (int d = 0; d < 64; ++d){
      float a = __shfl(aw[t], d, 64);
      xk += a * sWk[d*64 + lane];
      xs += a * sWs[d*64 + lane];
    }
    Xk[(size_t)row*64 + lane] = xk;
    Xs[(size_t)row*64 + lane] = xs;
  }
}

// ------------- K2b: transpose+convert  src f32 [2][4096][64] -> dst bf16 [2][64][4096]
__global__ __launch_bounds__(256) void k_tr(const float* __restrict__ src, u16* __restrict__ dst){
  __shared__ u16 sm[64][65];
  int tile = blockIdx.x;               // 128 tiles
  int b = tile >> 6, n0 = (tile & 63) * 64;
  int tid = threadIdx.x;
  int r = tid >> 2, seg = (tid & 3) * 16;
  const float* s = src + ((size_t)b*4096 + n0 + r) * 64 + seg;
  #pragma unroll
  for (int c = 0; c < 4; ++c){
    float4 v = ((const float4*)s)[c];
    sm[r][seg + c*4 + 0] = f2b(v.x);
    sm[r][seg + c*4 + 1] = f2b(v.y);
    sm[r][seg + c*4 + 2] = f2b(v.z);
    sm[r][seg + c*4 + 3] = f2b(v.w);
  }
  __syncthreads();
  int d = tid >> 2, ns = (tid & 3) * 16;
  u16* o = dst + (size_t)b*64*4096 + (size_t)d*4096 + n0 + ns;
  #pragma unroll
  for (int j = 0; j < 8; ++j){
    uint32_t lo = sm[ns + 2*j][d], hi = sm[ns + 2*j + 1][d];
    ((uint32_t*)o)[j] = lo | (hi << 16);
  }
}

// ---- K3: MFMA masked-sum. sums[b*4096+xoff+r][d] += sum_j (M1[r,j](&&M2)!=0)*X[j][d]
// Tile: 64 rows x 64 d, K-step 64, double-buffered LDS, atomic fp32 output.
template<bool TWO>
__global__ __launch_bounds__(256) void k_mm(
    const float* __restrict__ M1, const float* __restrict__ M2,
    const u16* __restrict__ XT, float* __restrict__ sums,
    int rowsPB, int cols, int numRT, int kspan, int xoff){
  __shared__ u16 Bm[2][64*72];   // mask tile bf16, padded stride 72
  __shared__ u16 Ax[2][64*72];   // XT tile bf16
  int rt = blockIdx.x % numRT;
  int ks = blockIdx.x / numRT;
  int rr0 = rt * 64;
  int b = rr0 / rowsPB, r0 = rr0 % rowsPB;
  int k0 = ks * kspan;
  int tid = threadIdx.x;
  int rsub = tid >> 2, seg = tid & 3, kk = seg * 16;
  const float* m1t = M1 + ((size_t)b*rowsPB + r0 + rsub) * cols + k0 + kk;
  const float* m2t = TWO ? (M2 + ((size_t)b*rowsPB + r0 + rsub) * cols + k0 + kk) : nullptr;
  const u16*   xtt = XT + (size_t)b*64*4096 + (size_t)rsub*4096 + xoff + k0 + kk;
  int lane = tid & 63, w = tid >> 6, quad = lane >> 4, l15 = lane & 15;

  f32x4 acc[4] = {f32x4{0,0,0,0}, f32x4{0,0,0,0}, f32x4{0,0,0,0}, f32x4{0,0,0,0}};
  int niter = kspan >> 6;

  float4 am0, am1, am2, am3, bn0, bn1, bn2, bn3;
  uint4 x0, x1;

#define ISSUE(IT) do{ size_t off = (size_t)(IT) * 64;                         \
    am0 = ((const float4*)(m1t + off))[0]; am1 = ((const float4*)(m1t + off))[1]; \
    am2 = ((const float4*)(m1t + off))[2]; am3 = ((const float4*)(m1t + off))[3]; \
    if (TWO){                                                                  \
      bn0 = ((const float4*)(m2t + off))[0]; bn1 = ((const float4*)(m2t + off))[1]; \
      bn2 = ((const float4*)(m2t + off))[2]; bn3 = ((const float4*)(m2t + off))[3]; \
    }                                                                          \
    x0 = ((const uint4*)(xtt + off))[0]; x1 = ((const uint4*)(xtt + off))[1]; }while(0)

#define PK(a, bb) (TWO ? ((nzb(a.x) && nzb(bb.x) ? 0x3F80u : 0u) | ((nzb(a.y) && nzb(bb.y) ? 0x3F80u : 0u) << 16)) \
                       : (nzb(a.x) | (nzb(a.y) << 16)))
#define PK2(a, bb) (TWO ? ((nzb(a.z) && nzb(bb.z) ? 0x3F80u : 0u) | ((nzb(a.w) && nzb(bb.w) ? 0x3F80u : 0u) << 16)) \
                        : (nzb(a.z) | (nzb(a.w) << 16)))

#define COMMIT(BUF) do{                                                        \
    uint4 pa, pb;                                                              \
    pa.x = PK(am0, bn0); pa.y = PK2(am0, bn0); pa.z = PK(am1, bn1); pa.w = PK2(am1, bn1); \
    pb.x = PK(am2, bn2); pb.y = PK2(am2, bn2); pb.z = PK(am3, bn3); pb.w = PK2(am3, bn3); \
    *(uint4*)&Bm[BUF][rsub*72 + kk]     = pa;                                  \
    *(uint4*)&Bm[BUF][rsub*72 + kk + 8] = pb;                                  \
    *(uint4*)&Ax[BUF][rsub*72 + kk]     = x0;                                  \
    *(uint4*)&Ax[BUF][rsub*72 + kk + 8] = x1; }while(0)

  ISSUE(0);
  COMMIT(0);
  __syncthreads();
  for (int it = 0; it < niter; ++it){
    int buf = it & 1;
    if (it + 1 < niter) ISSUE(it + 1);
    #pragma unroll
    for (int s = 0; s < 2; ++s){
      int ko = s*32 + quad*8;
      bf16x8 bfr = *(const bf16x8*)&Bm[buf][(w*16 + l15)*72 + ko];
      #pragma unroll
      for (int m = 0; m < 4; ++m){
        bf16x8 afr = *(const bf16x8*)&Ax[buf][(m*16 + l15)*72 + ko];
        acc[m] = __builtin_amdgcn_mfma_f32_16x16x32_bf16(afr, bfr, acc[m], 0, 0, 0);
      }
    }
    if (it + 1 < niter) COMMIT((it + 1) & 1);
    __syncthreads();
  }
  float* od = sums + (size_t)(b*4096 + xoff + r0 + w*16 + l15) * 64;
  #pragma unroll
  for (int m = 0; m < 4; ++m)
    #pragma unroll
    for (int g = 0; g < 4; ++g)
      atomicAdd(&od[m*16 + quad*4 + g], acc[m][g]);
#undef ISSUE
#undef COMMIT
#undef PK
#undef PK2
}

// ------------- K4: l2-normalize sums rows (deg cancels in l2n(mean))
__global__ __launch_bounds__(256) void k_norm(
    const float* __restrict__ sb, const float* __restrict__ sd,
    float* __restrict__ wwkn, float* __restrict__ wwsn){
  int idx = blockIdx.x*4 + (threadIdx.x >> 6);
  int lane = threadIdx.x & 63;
  const float* s; float* d;
  if (idx < 8192){ s = sb + (size_t)idx*64; d = wwkn + (size_t)idx*64; }
  else           { s = sd + (size_t)(idx - 8192)*64; d = wwsn + (size_t)(idx - 8192)*64; }
  float v = s[lane];
  float ss = v * v;
  #pragma unroll
  for (int o = 32; o > 0; o >>= 1) ss += __shfl_xor(ss, o, 64);
  d[lane] = v / (sqrtf(ss) + 1e-30f);
}

// -------------------- K5: forget gate + update; packed bf16-pair weights in LDS
__global__ __launch_bounds__(256, 2) void k_update(
    const float* __restrict__ w0, const float* __restrict__ w1,
    const float* __restrict__ gw, const float* __restrict__ ghat,
    const float* __restrict__ wwkn, const float* __restrict__ wwsn,
    const float* __restrict__ Wf, const float* __restrict__ bf,
    const float* __restrict__ Wupd, const float* __restrict__ bupd,
    float* __restrict__ out, float* __restrict__ WU){
  __shared__ uint32_t pWf[128*64];
  __shared__ uint32_t pWu[96*64];
  __shared__ float xsh[4][256];
  int tid = threadIdx.x;
  for (int i = tid; i < 8192; i += 256){
    int k2 = i >> 6, ln = i & 63;
    pWf[i] = (uint32_t)f2b(Wf[(2*k2)*64 + ln]) | ((uint32_t)f2b(Wf[(2*k2+1)*64 + ln]) << 16);
  }
  for (int i = tid; i < 6144; i += 256){
    int k2 = i >> 6, ln = i & 63;
    pWu[i] = (uint32_t)f2b(Wupd[(2*k2)*64 + ln]) | ((uint32_t)f2b(Wupd[(2*k2+1)*64 + ln]) << 16);
  }
  __syncthreads();
  int lane = tid & 63, wave = tid >> 6;
  float bff = bf[lane], bup = bupd[lane];
  float aw[4], wgv[4], wk[4], wsv[4];
  #pragma unroll
  for (int t = 0; t < 4; ++t){
    int row = blockIdx.x*4 + wave + t*2048;
    int b = row >> 12, n = row & 4095;
    aw[t] = (n < 2048) ? w0[((size_t)(b*2048 + n))*64 + lane]
                       : w1[((size_t)(b*2048 + n - 2048))*64 + lane];
    float gvv = gw[b*4096 + n];
    wgv[t] = (gvv != 0.f) ? ghat[b*64 + lane] : 0.f;
    wk[t]  = wwkn[(size_t)row*64 + lane];
    wsv[t] = wwsn[(size_t)row*64 + lane];
  }
  #pragma unroll
  for (int t = 0; t < 4; ++t){
    int row = blockIdx.x*4 + wave + t*2048;
    int b = row >> 12, n = row & 4095;
    xsh[wave][lane] = aw[t]; xsh[wave][64 + lane] = wgv[t];
    xsh[wave][128 + lane] = wk[t]; xsh[wave][192 + lane] = wsv[t];
    float f = bff, u = bup;
    #pragma unroll 8
    for (int k2 = 0; k2 < 32; ++k2){
      float2 xv = *(const float2*)&xsh[wave][2*k2];
      uint32_t wf = pWf[k2*64 + lane];
      f += xv.x * b2f((u16)wf) + xv.y * b2f((u16)(wf >> 16));
    }
    #pragma unroll 8
    for (int k2 = 32; k2 < 128; ++k2){
      float2 xv = *(const float2*)&xsh[wave][2*k2];
      uint32_t wf = pWf[k2*64 + lane];
      uint32_t wu = pWu[(k2 - 32)*64 + lane];
      f += xv.x * b2f((u16)wf) + xv.y * b2f((u16)(wf >> 16));
      u += xv.x * b2f((u16)wu) + xv.y * b2f((u16)(wu >> 16));
    }
    f = sigmoidf(f);
    u = fmaxf(u, 0.f);
    float wu = fmaxf(f, 0.2f) * aw[t] + (1.f - f) * u;
    out[((size_t)b*4224 + n)*64 + lane] = wu;
    WU[(size_t)row*64 + lane] = wu;
  }
}

// -------------------- K5b: WUo = WU @ Wo + bo
__global__ __launch_bounds__(256) void k_wuo(
    const float* __restrict__ WU, const float* __restrict__ Wo,
    const float* __restrict__ bo, float* __restrict__ WUo){
  __shared__ float sWo[4096];
  int tid = threadIdx.x;
  for (int i = tid; i < 1024; i += 256) ((float4*)sWo)[i] = ((const float4*)Wo)[i];
  __syncthreads();
  int lane = tid & 63, wave = tid >> 6;
  float boo = bo[lane];
  float wu[4];
  #pragma unroll
  for (int t = 0; t < 4; ++t){
    int row = blockIdx.x*4 + wave + t*2048;
    wu[t] = WU[(size_t)row*64 + lane];
  }
  #pragma unroll
  for (int t = 0; t < 4; ++t){
    int row = blockIdx.x*4 + wave + t*2048;
    float o = boo;
    #pragma unroll 8
    for (int d = 0; d < 64; ++d) o += __shfl(wu[t], d, 64) * sWo[d*64 + lane];
    WUo[(size_t)row*64 + lane] = o;
  }
}

// ------------------- K6: word_op[b,o,:] = (sum_n wes[n]*wop[n,o]!=0 * WUo[n,:]) / nnz
__global__ __launch_bounds__(256) void k_opagg(
    const float* __restrict__ wes, const float* __restrict__ wop,
    const float* __restrict__ WUo, float* __restrict__ wordop){
  __shared__ int q[4][1024];
  __shared__ float sacc[4][64];
  __shared__ int scnt[4];
  int blk = blockIdx.x;
  int b = blk >> 7, o = blk & 127;
  int lane = threadIdx.x & 63, wave = threadIdx.x >> 6;
  const float* wesb = wes + b*4096 + wave*1024;
  const float* Xb = WUo + (size_t)b*4096*64 + lane;
  uint4 av[4]; float wv[16];
  #pragma unroll
  for (int c = 0; c < 4; ++c) av[c] = ((const uint4*)wesb)[c*64 + lane];
  #pragma unroll
  for (int c = 0; c < 4; ++c)
    #pragma unroll
    for (int s = 0; s < 4; ++s)
      wv[c*4 + s] = wop[(size_t)(b*4096 + wave*1024 + c*256 + lane*4 + s)*128 + o];
  u64 lt = (1ULL << lane) - 1ULL;
  int cnt = 0;
  #pragma unroll
  for (int c = 0; c < 4; ++c){
    #pragma unroll
    for (int s = 0; s < 4; ++s){
      uint32_t wa = (s==0)?av[c].x:(s==1)?av[c].y:(s==2)?av[c].z:av[c].w;
      bool nz = ((wa & 0x7fffffffu) != 0) && (wv[c*4 + s] != 0.f);
      u64 m = __ballot(nz);
      if (nz) q[wave][cnt + (int)__popcll(m & lt)] = wave*1024 + c*256 + lane*4 + s;
      cnt += (int)__popcll(m);
    }
  }
  float acc = 0.f;
  int i = 0;
  for (; i + 8 <= cnt; i += 8){
    int4 c0 = *(const int4*)&q[wave][i];
    int4 c1 = *(const int4*)&q[wave][i + 4];
    float v0 = Xb[(size_t)c0.x*64], v1 = Xb[(size_t)c0.y*64];
    float v2 = Xb[(size_t)c0.z*64], v3 = Xb[(size_t)c0.w*64];
    float v4 = Xb[(size_t)c1.x*64], v5 = Xb[(size_t)c1.y*64];
    float v6 = Xb[(size_t)c1.z*64], v7 = Xb[(size_t)c1.w*64];
    acc += ((v0 + v1) + (v2 + v3)) + ((v4 + v5) + (v6 + v7));
  }
  for (; i < cnt; ++i) acc += Xb[(size_t)q[wave][i]*64];
  sacc[wave][lane] = acc;
  if (lane == 0) scnt[wave] = cnt;
  __syncthreads();
  if (wave == 0){
    float t = sacc[0][lane] + sacc[1][lane] + sacc[2][lane] + sacc[3][lane];
    float deg = (float)(scnt[0] + scnt[1] + scnt[2] + scnt[3]);
    wordop[(size_t)blk*64 + lane] = t / (deg + 1e-30f);
  }
}

// ----------------------------------------------------- K7: op_out epilogue
__global__ __launch_bounds__(256) void k_opout(
    const float* __restrict__ opE, const float* __restrict__ wordop,
    const float* __restrict__ Wf2, const float* __restrict__ bf2,
    const float* __restrict__ Wout, const float* __restrict__ bout,
    float* __restrict__ out){
  __shared__ float sW2[8192];
  __shared__ float sWo[4096];
  __shared__ float xsh[4][128];
  int tid = threadIdx.x;
  for (int i = tid; i < 2048; i += 256) ((float4*)sW2)[i] = ((const float4*)Wf2)[i];
  for (int i = tid; i < 1024; i += 256) ((float4*)sWo)[i] = ((const float4*)Wout)[i];
  __syncthreads();
  int lane = tid & 63, wave = tid >> 6;
  int row = blockIdx.x*4 + wave;
  int b = row >> 7, o = row & 127;
  float e  = opE[(size_t)row*64 + lane];
  float wo = wordop[(size_t)row*64 + lane];
  xsh[wave][lane] = e; xsh[wave][64 + lane] = wo;
  float f = bf2[lane], u = bout[lane];
  #pragma unroll 8
  for (int k = 0; k < 128; ++k) f += xsh[wave][k] * sW2[k*64 + lane];
  #pragma unroll 8
  for (int d = 0; d < 64; ++d)  u += xsh[wave][64 + d] * sWo[d*64 + lane];
  f = sigmoidf(f);
  u = fmaxf(u, 0.f);
  float res = fmaxf(f, 0.2f) * e + (1.f - f) * u;
  out[((size_t)b*4224 + 4096 + o)*64 + lane] = res;
}

extern "C" void kernel_launch(void* const* d_in, const int* in_sizes, int n_in,
                              void* d_out, int out_size, void* d_ws, size_t ws_size,
                              hipStream_t stream){
  const float* w0   = (const float*)d_in[0];
  const float* w1   = (const float*)d_in[1];
  const float* nh   = (const float*)d_in[2];
  const float* opE  = (const float*)d_in[3];
  const float* wes  = (const float*)d_in[4];
  const float* wem  = (const float*)d_in[5];
  const float* wop  = (const float*)d_in[6];
  const float* ww   = (const float*)d_in[7];
  const float* d0   = (const float*)d_in[8];
  const float* d1   = (const float*)d_in[9];
  const float* gw   = (const float*)d_in[10];
  const float* Wg   = (const float*)d_in[11];
  const float* bg   = (const float*)d_in[12];
  const float* Wwk  = (const float*)d_in[13];
  const float* bwk  = (const float*)d_in[14];
  const float* Wws  = (const float*)d_in[15];
  const float* bws  = (const float*)d_in[16];
  const float* Wo   = (const float*)d_in[17];
  const float* bo   = (const float*)d_in[18];
  const float* Wupd = (const float*)d_in[19];
  const float* bupd = (const float*)d_in[20];
  const float* Wf   = (const float*)d_in[21];
  const float* bf   = (const float*)d_in[22];
  const float* Wf2  = (const float*)d_in[23];
  const float* bf2  = (const float*)d_in[24];
  const float* Wout = (const float*)d_in[25];
  const float* bout = (const float*)d_in[26];

  float* ws   = (float*)d_ws;
  float* ghat = ws;                         // 128
  float* Xk   = ghat + 128;                 // 524288  (-> sums_big -> WU)
  float* Xs   = Xk + 524288;                // 524288  (-> sums_dep -> WUo)
  float* wwkn = Xs + 524288;                // 524288
  float* wwsn = wwkn + 524288;              // 524288
  float* wopm = wwsn + 524288;              // 16384
  u16*  XkT   = (u16*)(wopm + 16384);       // 524288 ush (= 262144 f32)
  u16*  XsT   = (u16*)(wopm + 16384 + 262144); // 524288 ush
  float* sums_big = Xk;
  float* sums_dep = Xs;
  float* WU   = Xk;
  float* WUo  = Xs;
  float* out  = (float*)d_out;

  k_pre<<<1, 128, 0, stream>>>(nh, Wg, bg, ghat);
  k_xform<<<512, 256, 0, stream>>>(w0, w1, Wwk, bwk, Wws, bws, Xk, Xs);
  k_tr<<<128, 256, 0, stream>>>(Xk, XkT);
  k_tr<<<128, 256, 0, stream>>>(Xs, XsT);
  hipMemsetAsync(sums_big, 0, 524288 * sizeof(float), stream);
  hipMemsetAsync(sums_dep, 0, 524288 * sizeof(float), stream);
  // big: rowsPB=4096, cols=4096, numRT=128, KS=8 -> kspan=512, grid 1024
  k_mm<true ><<<1024, 256, 0, stream>>>(ww, wem, XkT, sums_big, 4096, 4096, 128, 512, 0);
  // depends: rowsPB=2048, cols=2048, numRT=64, KS=4 -> kspan=512, grid 256 each
  k_mm<false><<<256, 256, 0, stream>>>(d0, nullptr, XsT, sums_dep, 2048, 2048, 64, 512, 0);
  k_mm<false><<<256, 256, 0, stream>>>(d1, nullptr, XsT, sums_dep, 2048, 2048, 64, 512, 2048);
  k_norm<<<4096, 256, 0, stream>>>(sums_big, sums_dep, wwkn, wwsn);
  k_update<<<512, 256, 0, stream>>>(w0, w1, gw, ghat, wwkn, wwsn, Wf, bf, Wupd, bupd, out, WU);
  k_wuo<<<512, 256, 0, stream>>>(WU, Wo, bo, WUo);
  k_opagg<<<256, 256, 0, stream>>>(wes, wop, WUo, wopm);
  k_opout<<<64, 256, 0, stream>>>(opE, wopm, Wf2, bf2, Wout, bout, out);
}

// Round 5
// 507.374 us; speedup vs baseline: 1.0246x; 1.0246x over previous
//
#include <hip/hip_runtime.h>
#include <cstdint>

typedef unsigned short u16;
typedef unsigned long long u64;

__device__ __forceinline__ u16 f2b(float f){
  union { float f; uint32_t i; } v; v.f = f;
  uint32_t r = v.i + 0x7FFFu + ((v.i >> 16) & 1u);   // RNE
  return (u16)(r >> 16);
}
__device__ __forceinline__ float b2f(u16 u){
  union { uint32_t i; float f; } v; v.i = ((uint32_t)u) << 16; return v.f;
}
__device__ __forceinline__ float sigmoidf(float x){ return 1.0f / (1.0f + __expf(-x)); }

// ---------------------------------------------------------------- K1: ghat[b,h]
__global__ void k_pre(const float* __restrict__ nh, const float* __restrict__ Wg,
                      const float* __restrict__ bg, float* __restrict__ ghat){
  int b = threadIdx.x >> 6, h = threadIdx.x & 63;
  float g = bg[h];
  for (int d = 0; d < 64; ++d) g += nh[b*64 + d] * Wg[d*64 + h];
  float ss = g * g;
  #pragma unroll
  for (int o = 32; o > 0; o >>= 1) ss += __shfl_xor(ss, o, 64);
  ghat[b*64 + h] = g / (sqrtf(ss) + 1e-30f);
}

// ------------------------------------------- K2: Xk = all_w@Wwk+bwk, Xs = all_w@Wws+bws
__global__ __launch_bounds__(256) void k_xform(
    const float* __restrict__ w0, const float* __restrict__ w1,
    const float* __restrict__ Wwk, const float* __restrict__ bwk,
    const float* __restrict__ Wws, const float* __restrict__ bws,
    float* __restrict__ Xk, float* __restrict__ Xs){
  __shared__ float sWk[4096], sWs[4096];
  int tid = threadIdx.x;
  for (int i = tid; i < 1024; i += 256){
    ((float4*)sWk)[i] = ((const float4*)Wwk)[i];
    ((float4*)sWs)[i] = ((const float4*)Wws)[i];
  }
  __syncthreads();
  int lane = tid & 63, wave = tid >> 6;
  float bk = bwk[lane], bs = bws[lane];
  float aw[4];
  #pragma unroll
  for (int t = 0; t < 4; ++t){
    int row = blockIdx.x*4 + wave + t*2048;
    int b = row >> 12, n = row & 4095;
    aw[t] = (n < 2048) ? w0[((size_t)(b*2048 + n))*64 + lane]
                       : w1[((size_t)(b*2048 + n - 2048))*64 + lane];
  }
  #pragma unroll
  for (int t = 0; t < 4; ++t){
    int row = blockIdx.x*4 + wave + t*2048;
    float xk = bk, xs = bs;
    #pragma unroll 8
    for (int d = 0; d < 64; ++d){
      float a = __shfl(aw[t], d, 64);
      xk += a * sWk[d*64 + lane];
      xs += a * sWs[d*64 + lane];
    }
    Xk[(size_t)row*64 + lane] = xk;
    Xs[(size_t)row*64 + lane] = xs;
  }
}

// ---- K3: streaming bitmask build. One wave per row; JS j-steps of 256 cols each.
// Word l of a row is built at step j=l>>2, slot s=l&3; ballot bit p <-> col j*256+p*4+s.
template<bool TWO, int JS>
__global__ __launch_bounds__(256) void k_bits(
    const float* __restrict__ A, const float* __restrict__ B, u64* __restrict__ bits){
  int lane = threadIdx.x & 63, wave = threadIdx.x >> 6;
  int row = blockIdx.x*4 + wave;
  const float* a = A + (size_t)row * (JS*256) + lane*4;
  const float* bb = TWO ? (B + (size_t)row * (JS*256) + lane*4) : nullptr;
  u64 myword = 0;
  #pragma unroll 4
  for (int j = 0; j < JS; ++j){
    float4 va = *(const float4*)(a + j*256);
    float4 vb;
    if (TWO) vb = *(const float4*)(bb + j*256);
    #pragma unroll
    for (int s = 0; s < 4; ++s){
      float x = (s==0)?va.x:(s==1)?va.y:(s==2)?va.z:va.w;
      bool nz = (x != 0.f);
      if (TWO){
        float y = (s==0)?vb.x:(s==1)?vb.y:(s==2)?vb.z:vb.w;
        nz = nz && (y != 0.f);
      }
      u64 m = __ballot(nz);
      if (lane == j*4 + s) myword = m;
    }
  }
  if (lane < JS*4) bits[(size_t)row*(JS*4) + lane] = myword;
}

// ---- K3b: wes & wop -> bitOp[b][n][2] (word = o&1, bit = o>>1)
__global__ __launch_bounds__(256) void k_bitsop(
    const float* __restrict__ wes, const float* __restrict__ wop, u64* __restrict__ bitOp){
  int lane = threadIdx.x & 63, wave = threadIdx.x >> 6;
  int wg = blockIdx.x*4 + wave;                 // 512 waves, 16 n's each
  for (int it = 0; it < 16; ++it){
    int ng = wg*16 + it;                        // b*4096 + n
    float2 v = ((const float2*)(wop + (size_t)ng*128))[lane];
    float e = wes[ng];
    u64 m0 = __ballot(e != 0.f && v.x != 0.f);
    u64 m1 = __ballot(e != 0.f && v.y != 0.f);
    if (lane == 0) bitOp[(size_t)ng*2]     = m0;
    if (lane == 1) bitOp[(size_t)ng*2 + 1] = m1;
  }
}

// ---- K4: gather+sum+l2n from bitmask. One wave per row; deg cancels under l2n.
__global__ __launch_bounds__(256) void k_gath(
    const u64* __restrict__ bits, const float* __restrict__ X,
    u16* __restrict__ outp, int rowsPB, int WPR, int xoff){
  __shared__ int q[4][256];
  int lane = threadIdx.x & 63, wave = threadIdx.x >> 6;
  int rowIdx = blockIdx.x*4 + wave;
  int b = rowIdx / rowsPB, r = rowIdx - b*rowsPB;
  u64 word = (lane < WPR) ? bits[(size_t)rowIdx*WPR + lane] : 0ULL;
  int c = __popcll(word);
  int pre = c;
  #pragma unroll
  for (int off = 1; off < 64; off <<= 1){
    int t = __shfl_up(pre, off, 64);
    if (lane >= off) pre += t;
  }
  int total = __shfl(pre, 63, 64);
  int base = pre - c;
  int colhi = (lane >> 2) * 256 + (lane & 3);
  u64 m = word;
  while (m){
    int p = __builtin_ctzll(m); m &= m - 1;
    q[wave][base++] = colhi + p*4;
  }
  __syncthreads();
  const float* Xb = X + ((size_t)b*4096 + xoff)*64 + lane;
  float acc = 0.f;
  int i = 0;
  for (; i + 8 <= total; i += 8){
    int4 c0 = *(const int4*)&q[wave][i];
    int4 c1 = *(const int4*)&q[wave][i + 4];
    float v0 = Xb[(size_t)c0.x*64], v1 = Xb[(size_t)c0.y*64];
    float v2 = Xb[(size_t)c0.z*64], v3 = Xb[(size_t)c0.w*64];
    float v4 = Xb[(size_t)c1.x*64], v5 = Xb[(size_t)c1.y*64];
    float v6 = Xb[(size_t)c1.z*64], v7 = Xb[(size_t)c1.w*64];
    acc += ((v0 + v1) + (v2 + v3)) + ((v4 + v5) + (v6 + v7));
  }
  for (; i < total; ++i) acc += Xb[(size_t)q[wave][i]*64];
  float ss = acc * acc;
  #pragma unroll
  for (int o = 32; o > 0; o >>= 1) ss += __shfl_xor(ss, o, 64);
  outp[((size_t)b*4096 + xoff + r)*64 + lane] = f2b(acc / (sqrtf(ss) + 1e-30f));
}

// -------------------- K5: forget gate + update; packed bf16-pair weights in LDS
__global__ __launch_bounds__(256, 2) void k_update(
    const float* __restrict__ w0, const float* __restrict__ w1,
    const float* __restrict__ gw, const float* __restrict__ ghat,
    const u16* __restrict__ wwkn, const u16* __restrict__ wwsn,
    const float* __restrict__ Wf, const float* __restrict__ bf,
    const float* __restrict__ Wupd, const float* __restrict__ bupd,
    float* __restrict__ out, float* __restrict__ WU){
  __shared__ uint32_t pWf[128*64];
  __shared__ uint32_t pWu[96*64];
  __shared__ float xsh[4][256];
  int tid = threadIdx.x;
  for (int i = tid; i < 8192; i += 256){
    int k2 = i >> 6, ln = i & 63;
    pWf[i] = (uint32_t)f2b(Wf[(2*k2)*64 + ln]) | ((uint32_t)f2b(Wf[(2*k2+1)*64 + ln]) << 16);
  }
  for (int i = tid; i < 6144; i += 256){
    int k2 = i >> 6, ln = i & 63;
    pWu[i] = (uint32_t)f2b(Wupd[(2*k2)*64 + ln]) | ((uint32_t)f2b(Wupd[(2*k2+1)*64 + ln]) << 16);
  }
  __syncthreads();
  int lane = tid & 63, wave = tid >> 6;
  float bff = bf[lane], bup = bupd[lane];
  float aw[4], wgv[4], wk[4], wsv[4];
  #pragma unroll
  for (int t = 0; t < 4; ++t){
    int row = blockIdx.x*4 + wave + t*2048;
    int b = row >> 12, n = row & 4095;
    aw[t] = (n < 2048) ? w0[((size_t)(b*2048 + n))*64 + lane]
                       : w1[((size_t)(b*2048 + n - 2048))*64 + lane];
    float gvv = gw[b*4096 + n];
    wgv[t] = (gvv != 0.f) ? ghat[b*64 + lane] : 0.f;
    wk[t]  = b2f(wwkn[(size_t)row*64 + lane]);
    wsv[t] = b2f(wwsn[(size_t)row*64 + lane]);
  }
  #pragma unroll
  for (int t = 0; t < 4; ++t){
    int row = blockIdx.x*4 + wave + t*2048;
    int b = row >> 12, n = row & 4095;
    xsh[wave][lane] = aw[t]; xsh[wave][64 + lane] = wgv[t];
    xsh[wave][128 + lane] = wk[t]; xsh[wave][192 + lane] = wsv[t];
    float f = bff, u = bup;
    #pragma unroll 8
    for (int k2 = 0; k2 < 32; ++k2){
      float2 xv = *(const float2*)&xsh[wave][2*k2];
      uint32_t wf = pWf[k2*64 + lane];
      f += xv.x * b2f((u16)wf) + xv.y * b2f((u16)(wf >> 16));
    }
    #pragma unroll 8
    for (int k2 = 32; k2 < 128; ++k2){
      float2 xv = *(const float2*)&xsh[wave][2*k2];
      uint32_t wf = pWf[k2*64 + lane];
      uint32_t wu = pWu[(k2 - 32)*64 + lane];
      f += xv.x * b2f((u16)wf) + xv.y * b2f((u16)(wf >> 16));
      u += xv.x * b2f((u16)wu) + xv.y * b2f((u16)(wu >> 16));
    }
    f = sigmoidf(f);
    u = fmaxf(u, 0.f);
    float wu = fmaxf(f, 0.2f) * aw[t] + (1.f - f) * u;
    out[((size_t)b*4224 + n)*64 + lane] = wu;
    WU[(size_t)row*64 + lane] = wu;
  }
}

// -------------------- K5b: WUo = WU @ Wo + bo
__global__ __launch_bounds__(256) void k_wuo(
    const float* __restrict__ WU, const float* __restrict__ Wo,
    const float* __restrict__ bo, float* __restrict__ WUo){
  __shared__ float sWo[4096];
  int tid = threadIdx.x;
  for (int i = tid; i < 1024; i += 256) ((float4*)sWo)[i] = ((const float4*)Wo)[i];
  __syncthreads();
  int lane = tid & 63, wave = tid >> 6;
  float boo = bo[lane];
  float wu[4];
  #pragma unroll
  for (int t = 0; t < 4; ++t){
    int row = blockIdx.x*4 + wave + t*2048;
    wu[t] = WU[(size_t)row*64 + lane];
  }
  #pragma unroll
  for (int t = 0; t < 4; ++t){
    int row = blockIdx.x*4 + wave + t*2048;
    float o = boo;
    #pragma unroll 8
    for (int d = 0; d < 64; ++d) o += __shfl(wu[t], d, 64) * sWo[d*64 + lane];
    WUo[(size_t)row*64 + lane] = o;
  }
}

// ------------------- K6: word_op from bitOp; divide by popcount
__global__ __launch_bounds__(256) void k_opagg(
    const u64* __restrict__ bitOp, const float* __restrict__ WUo,
    float* __restrict__ wordop){
  __shared__ int q[4][256];
  int lane = threadIdx.x & 63, wave = threadIdx.x >> 6;
  int rowIdx = blockIdx.x*4 + wave;       // b*128 + o
  int b = rowIdx >> 7, o = rowIdx & 127;
  int wrd = o & 1, bit = o >> 1;
  const u64* bp = bitOp + (size_t)b*4096*2 + wrd;
  u64 lt = (1ULL << lane) - 1ULL;
  int cnt = 0;
  #pragma unroll 4
  for (int it = 0; it < 64; ++it){
    int n = it*64 + lane;
    u64 v = bp[(size_t)n*2];
    bool nz = (v >> bit) & 1ULL;
    u64 m = __ballot(nz);
    if (nz) q[wave][cnt + (int)__popcll(m & lt)] = n;
    cnt += (int)__popcll(m);
  }
  __syncthreads();
  const float* Xb = WUo + (size_t)b*4096*64 + lane;
  float acc = 0.f;
  int i = 0;
  for (; i + 8 <= cnt; i += 8){
    int4 c0 = *(const int4*)&q[wave][i];
    int4 c1 = *(const int4*)&q[wave][i + 4];
    float v0 = Xb[(size_t)c0.x*64], v1 = Xb[(size_t)c0.y*64];
    float v2 = Xb[(size_t)c0.z*64], v3 = Xb[(size_t)c0.w*64];
    float v4 = Xb[(size_t)c1.x*64], v5 = Xb[(size_t)c1.y*64];
    float v6 = Xb[(size_t)c1.z*64], v7 = Xb[(size_t)c1.w*64];
    acc += ((v0 + v1) + (v2 + v3)) + ((v4 + v5) + (v6 + v7));
  }
  for (; i < cnt; ++i) acc += Xb[(size_t)q[wave][i]*64];
  wordop[(size_t)rowIdx*64 + lane] = acc / ((float)cnt + 1e-30f);
}

// ----------------------------------------------------- K7: op_out epilogue
__global__ __launch_bounds__(256) void k_opout(
    const float* __restrict__ opE, const float* __restrict__ wordop,
    const float* __restrict__ Wf2, const float* __restrict__ bf2,
    const float* __restrict__ Wout, const float* __restrict__ bout,
    float* __restrict__ out){
  __shared__ float sW2[8192];
  __shared__ float sWo[4096];
  __shared__ float xsh[4][128];
  int tid = threadIdx.x;
  for (int i = tid; i < 2048; i += 256) ((float4*)sW2)[i] = ((const float4*)Wf2)[i];
  for (int i = tid; i < 1024; i += 256) ((float4*)sWo)[i] = ((const float4*)Wout)[i];
  __syncthreads();
  int lane = tid & 63, wave = tid >> 6;
  int row = blockIdx.x*4 + wave;
  int b = row >> 7, o = row & 127;
  float e  = opE[(size_t)row*64 + lane];
  float wo = wordop[(size_t)row*64 + lane];
  xsh[wave][lane] = e; xsh[wave][64 + lane] = wo;
  float f = bf2[lane], u = bout[lane];
  #pragma unroll 8
  for (int k = 0; k < 128; ++k) f += xsh[wave][k] * sW2[k*64 + lane];
  #pragma unroll 8
  for (int d = 0; d < 64; ++d)  u += xsh[wave][64 + d] * sWo[d*64 + lane];
  f = sigmoidf(f);
  u = fmaxf(u, 0.f);
  float res = fmaxf(f, 0.2f) * e + (1.f - f) * u;
  out[((size_t)b*4224 + 4096 + o)*64 + lane] = res;
}

extern "C" void kernel_launch(void* const* d_in, const int* in_sizes, int n_in,
                              void* d_out, int out_size, void* d_ws, size_t ws_size,
                              hipStream_t stream){
  const float* w0   = (const float*)d_in[0];
  const float* w1   = (const float*)d_in[1];
  const float* nh   = (const float*)d_in[2];
  const float* opE  = (const float*)d_in[3];
  const float* wes  = (const float*)d_in[4];
  const float* wem  = (const float*)d_in[5];
  const float* wop  = (const float*)d_in[6];
  const float* ww   = (const float*)d_in[7];
  const float* d0   = (const float*)d_in[8];
  const float* d1   = (const float*)d_in[9];
  const float* gw   = (const float*)d_in[10];
  const float* Wg   = (const float*)d_in[11];
  const float* bg   = (const float*)d_in[12];
  const float* Wwk  = (const float*)d_in[13];
  const float* bwk  = (const float*)d_in[14];
  const float* Wws  = (const float*)d_in[15];
  const float* bws  = (const float*)d_in[16];
  const float* Wo   = (const float*)d_in[17];
  const float* bo   = (const float*)d_in[18];
  const float* Wupd = (const float*)d_in[19];
  const float* bupd = (const float*)d_in[20];
  const float* Wf   = (const float*)d_in[21];
  const float* bf   = (const float*)d_in[22];
  const float* Wf2  = (const float*)d_in[23];
  const float* bf2  = (const float*)d_in[24];
  const float* Wout = (const float*)d_in[25];
  const float* bout = (const float*)d_in[26];

  float* ws   = (float*)d_ws;
  float* ghat = ws;                              // 128
  float* Xk   = ws + 128;                        // 524288
  float* Xs   = ws + 524416;                     // 524288
  float* wopm = ws + 1048704;                    // 16384
  u16*  wwkn  = (u16*)(ws + 1065088);            // 524288 u16
  u16*  wwsn  = (u16*)(ws + 1327232);            // 524288 u16
  u64*  bitBig= (u64*)(ws + 1589376);            // 524288 u64
  u64*  bitD0 = (u64*)(ws + 2637952);            // 131072 u64
  u64*  bitD1 = (u64*)(ws + 2900096);            // 131072 u64
  u64*  bitOp = (u64*)(ws + 3162240);            // 16384 u64
  float* WU   = Xk;                              // Xk dead after big gather
  float* WUo  = Xs;                              // Xs dead after dep gathers
  float* out  = (float*)d_out;

  k_pre<<<1, 128, 0, stream>>>(nh, Wg, bg, ghat);
  k_xform<<<512, 256, 0, stream>>>(w0, w1, Wwk, bwk, Wws, bws, Xk, Xs);
  k_bits<true , 16><<<2048, 256, 0, stream>>>(ww, wem, bitBig);   // 8192 rows x 4096
  k_bits<false, 8 ><<<1024, 256, 0, stream>>>(d0, nullptr, bitD0); // 4096 rows x 2048
  k_bits<false, 8 ><<<1024, 256, 0, stream>>>(d1, nullptr, bitD1);
  k_bitsop<<<128, 256, 0, stream>>>(wes, wop, bitOp);
  k_gath<<<2048, 256, 0, stream>>>(bitBig, Xk, wwkn, 4096, 64, 0);
  k_gath<<<1024, 256, 0, stream>>>(bitD0, Xs, wwsn, 2048, 32, 0);
  k_gath<<<1024, 256, 0, stream>>>(bitD1, Xs, wwsn, 2048, 32, 2048);
  k_update<<<512, 256, 0, stream>>>(w0, w1, gw, ghat, wwkn, wwsn, Wf, bf, Wupd, bupd, out, WU);
  k_wuo<<<512, 256, 0, stream>>>(WU, Wo, bo, WUo);
  k_opagg<<<64, 256, 0, stream>>>(bitOp, WUo, wopm);
  k_opout<<<64, 256, 0, stream>>>(opE, wopm, Wf2, bf2, Wout, bout, out);
}

// Round 6
// 456.680 us; speedup vs baseline: 1.1383x; 1.1110x over previous
//
#include <hip/hip_runtime.h>
#include <cstdint>

typedef unsigned short u16;
typedef unsigned long long u64;

__device__ __forceinline__ u16 f2b(float f){
  union { float f; uint32_t i; } v; v.f = f;
  uint32_t r = v.i + 0x7FFFu + ((v.i >> 16) & 1u);   // RNE
  return (u16)(r >> 16);
}
__device__ __forceinline__ float b2f(u16 u){
  union { uint32_t i; float f; } v; v.i = ((uint32_t)u) << 16; return v.f;
}
__device__ __forceinline__ float sigmoidf(float x){ return 1.0f / (1.0f + __expf(-x)); }

// ---------------------------------------------------------------- K1: ghat[b,h]
__global__ void k_pre(const float* __restrict__ nh, const float* __restrict__ Wg,
                      const float* __restrict__ bg, float* __restrict__ ghat){
  int b = threadIdx.x >> 6, h = threadIdx.x & 63;
  float g = bg[h];
  for (int d = 0; d < 64; ++d) g += nh[b*64 + d] * Wg[d*64 + h];
  float ss = g * g;
  #pragma unroll
  for (int o = 32; o > 0; o >>= 1) ss += __shfl_xor(ss, o, 64);
  ghat[b*64 + h] = g / (sqrtf(ss) + 1e-30f);
}

// ------------------------------------------- K2: Xk = all_w@Wwk+bwk, Xs = all_w@Wws+bws
__global__ __launch_bounds__(256) void k_xform(
    const float* __restrict__ w0, const float* __restrict__ w1,
    const float* __restrict__ Wwk, const float* __restrict__ bwk,
    const float* __restrict__ Wws, const float* __restrict__ bws,
    float* __restrict__ Xk, float* __restrict__ Xs){
  __shared__ float sWk[4096], sWs[4096];
  int tid = threadIdx.x;
  for (int i = tid; i < 1024; i += 256){
    ((float4*)sWk)[i] = ((const float4*)Wwk)[i];
    ((float4*)sWs)[i] = ((const float4*)Wws)[i];
  }
  __syncthreads();
  int lane = tid & 63, wave = tid >> 6;
  float bk = bwk[lane], bs = bws[lane];
  float aw[4];
  #pragma unroll
  for (int t = 0; t < 4; ++t){
    int row = blockIdx.x*4 + wave + t*2048;
    int b = row >> 12, n = row & 4095;
    aw[t] = (n < 2048) ? w0[((size_t)(b*2048 + n))*64 + lane]
                       : w1[((size_t)(b*2048 + n - 2048))*64 + lane];
  }
  #pragma unroll
  for (int t = 0; t < 4; ++t){
    int row = blockIdx.x*4 + wave + t*2048;
    float xk = bk, xs = bs;
    #pragma unroll 8
    for (int d = 0; d < 64; ++d){
      float a = __shfl(aw[t], d, 64);
      xk += a * sWk[d*64 + lane];
      xs += a * sWs[d*64 + lane];
    }
    Xk[(size_t)row*64 + lane] = xk;
    Xs[(size_t)row*64 + lane] = xs;
  }
}

// ---- K3: ALL mask bitmasks, one dispatch. One wave = one 1024-col chunk,
// straight-line: 8 loads, 16 ballots, 1 store. wid<32768: ww&&wem; then d0; then d1 (B=A).
__global__ __launch_bounds__(256) void k_bits_all(
    const float* __restrict__ ww, const float* __restrict__ wem,
    const float* __restrict__ d0, const float* __restrict__ d1,
    u64* __restrict__ bitBig, u64* __restrict__ bitD0, u64* __restrict__ bitD1){
  int wid = blockIdx.x*4 + (threadIdx.x >> 6);
  int lane = threadIdx.x & 63;
  const float *A, *B; u64* dst;
  if (wid < 32768){
    A = ww + (size_t)wid*1024; B = wem + (size_t)wid*1024; dst = bitBig + (size_t)wid*16;
  } else if (wid < 40960){
    size_t c = wid - 32768; A = d0 + c*1024; B = A; dst = bitD0 + c*16;
  } else {
    size_t c = wid - 40960; A = d1 + c*1024; B = A; dst = bitD1 + c*16;
  }
  const float4* ap = (const float4*)A + lane;
  const float4* bp = (const float4*)B + lane;
  float4 a0 = ap[0], a1 = ap[64], a2 = ap[128], a3 = ap[192];
  float4 b0 = bp[0], b1 = bp[64], b2 = bp[128], b3 = bp[192];
  u64 myw = 0;
#define B4(i, va, vb) { \
  u64 m0 = __ballot((va.x != 0.f) && (vb.x != 0.f)); \
  u64 m1 = __ballot((va.y != 0.f) && (vb.y != 0.f)); \
  u64 m2 = __ballot((va.z != 0.f) && (vb.z != 0.f)); \
  u64 m3 = __ballot((va.w != 0.f) && (vb.w != 0.f)); \
  if (lane == (i)*4 + 0) myw = m0; \
  if (lane == (i)*4 + 1) myw = m1; \
  if (lane == (i)*4 + 2) myw = m2; \
  if (lane == (i)*4 + 3) myw = m3; }
  B4(0, a0, b0) B4(1, a1, b1) B4(2, a2, b2) B4(3, a3, b3)
#undef B4
  if (lane < 16) dst[lane] = myw;
}

// ---- K3b: wes & wop -> bitOp[b][n][2] (word = o&1, bit = o>>1). One wave per n.
__global__ __launch_bounds__(64) void k_bitsop(
    const float* __restrict__ wes, const float* __restrict__ wop, u64* __restrict__ bitOp){
  int lane = threadIdx.x;
  int ng = blockIdx.x;                          // b*4096 + n
  float2 v = ((const float2*)(wop + (size_t)ng*128))[lane];
  float e = wes[ng];
  u64 m0 = __ballot((e != 0.f) && (v.x != 0.f));
  u64 m1 = __ballot((e != 0.f) && (v.y != 0.f));
  if (lane == 0) bitOp[(size_t)ng*2]     = m0;
  if (lane == 1) bitOp[(size_t)ng*2 + 1] = m1;
}

// ---- K4: ALL gathers, one dispatch. One wave per output row; l2n folded in.
__global__ __launch_bounds__(256) void k_gath_all(
    const u64* __restrict__ bitBig, const u64* __restrict__ bitD0, const u64* __restrict__ bitD1,
    const float* __restrict__ Xk, const float* __restrict__ Xs,
    u16* __restrict__ wwkn, u16* __restrict__ wwsn){
  __shared__ int q[4][256];
  int lane = threadIdx.x & 63, wave = threadIdx.x >> 6;
  int wid = blockIdx.x*4 + wave;
  const u64* bits; const float* Xb; u16* op; int WPR;
  if (wid < 8192){
    WPR = 64; bits = bitBig + (size_t)wid*64;
    int b = wid >> 12;
    Xb = Xk + (size_t)b*4096*64 + lane;
    op = wwkn + (size_t)wid*64;
  } else if (wid < 12288){
    int lr = wid - 8192; WPR = 32; bits = bitD0 + (size_t)lr*32;
    int b = lr >> 11, r = lr & 2047;
    Xb = Xs + (size_t)b*4096*64 + lane;
    op = wwsn + ((size_t)b*4096 + r)*64;
  } else {
    int lr = wid - 12288; WPR = 32; bits = bitD1 + (size_t)lr*32;
    int b = lr >> 11, r = lr & 2047;
    Xb = Xs + ((size_t)b*4096 + 2048)*64 + lane;
    op = wwsn + ((size_t)b*4096 + 2048 + r)*64;
  }
  u64 word = (lane < WPR) ? bits[lane] : 0ULL;
  int c = __popcll(word);
  int pre = c;
  #pragma unroll
  for (int off = 1; off < 64; off <<= 1){
    int t = __shfl_up(pre, off, 64);
    if (lane >= off) pre += t;
  }
  int total = __shfl(pre, 63, 64);
  int base = pre - c;
  int colhi = (lane >> 2) * 256 + (lane & 3);
  u64 m = word;
  while (m){
    int p = __builtin_ctzll(m); m &= m - 1;
    q[wave][base++] = colhi + p*4;
  }
  __syncthreads();
  float acc = 0.f;
  int i = 0;
  for (; i + 8 <= total; i += 8){
    int4 c0 = *(const int4*)&q[wave][i];
    int4 c1 = *(const int4*)&q[wave][i + 4];
    float v0 = Xb[(size_t)c0.x*64], v1 = Xb[(size_t)c0.y*64];
    float v2 = Xb[(size_t)c0.z*64], v3 = Xb[(size_t)c0.w*64];
    float v4 = Xb[(size_t)c1.x*64], v5 = Xb[(size_t)c1.y*64];
    float v6 = Xb[(size_t)c1.z*64], v7 = Xb[(size_t)c1.w*64];
    acc += ((v0 + v1) + (v2 + v3)) + ((v4 + v5) + (v6 + v7));
  }
  for (; i < total; ++i) acc += Xb[(size_t)q[wave][i]*64];
  float ss = acc * acc;
  #pragma unroll
  for (int o = 32; o > 0; o >>= 1) ss += __shfl_xor(ss, o, 64);
  op[lane] = f2b(acc / (sqrtf(ss) + 1e-30f));
}

// -------------------- K5: gate + update + Wo projection (fused); bf16-pair weights in LDS
__global__ __launch_bounds__(256, 2) void k_update(
    const float* __restrict__ w0, const float* __restrict__ w1,
    const float* __restrict__ gw, const float* __restrict__ ghat,
    const u16* __restrict__ wwkn, const u16* __restrict__ wwsn,
    const float* __restrict__ Wf, const float* __restrict__ bf,
    const float* __restrict__ Wupd, const float* __restrict__ bupd,
    const float* __restrict__ Wo, const float* __restrict__ bo,
    float* __restrict__ out, float* __restrict__ WUo){
  __shared__ uint32_t pWf[8192];    // 32 KB
  __shared__ uint32_t pWu[6144];    // 24 KB
  __shared__ uint32_t pWo[2048];    // 8 KB
  __shared__ float xsh[4][256];     // 4 KB
  int tid = threadIdx.x;
  for (int i = tid; i < 8192; i += 256){
    int k2 = i >> 6, ln = i & 63;
    pWf[i] = (uint32_t)f2b(Wf[(2*k2)*64 + ln]) | ((uint32_t)f2b(Wf[(2*k2+1)*64 + ln]) << 16);
  }
  for (int i = tid; i < 6144; i += 256){
    int k2 = i >> 6, ln = i & 63;
    pWu[i] = (uint32_t)f2b(Wupd[(2*k2)*64 + ln]) | ((uint32_t)f2b(Wupd[(2*k2+1)*64 + ln]) << 16);
  }
  for (int i = tid; i < 2048; i += 256){
    int k2 = i >> 6, ln = i & 63;
    pWo[i] = (uint32_t)f2b(Wo[(2*k2)*64 + ln]) | ((uint32_t)f2b(Wo[(2*k2+1)*64 + ln]) << 16);
  }
  __syncthreads();
  int lane = tid & 63, wave = tid >> 6;
  float bff = bf[lane], bup = bupd[lane], boo = bo[lane];
  float aw[4], wgv[4], wk[4], wsv[4];
  #pragma unroll
  for (int t = 0; t < 4; ++t){
    int row = blockIdx.x*4 + wave + t*2048;
    int b = row >> 12, n = row & 4095;
    aw[t] = (n < 2048) ? w0[((size_t)(b*2048 + n))*64 + lane]
                       : w1[((size_t)(b*2048 + n - 2048))*64 + lane];
    float gvv = gw[b*4096 + n];
    wgv[t] = (gvv != 0.f) ? ghat[b*64 + lane] : 0.f;
    wk[t]  = b2f(wwkn[(size_t)row*64 + lane]);
    wsv[t] = b2f(wwsn[(size_t)row*64 + lane]);
  }
  #pragma unroll
  for (int t = 0; t < 4; ++t){
    int row = blockIdx.x*4 + wave + t*2048;
    int b = row >> 12, n = row & 4095;
    xsh[wave][lane] = aw[t]; xsh[wave][64 + lane] = wgv[t];
    xsh[wave][128 + lane] = wk[t]; xsh[wave][192 + lane] = wsv[t];
    float f = bff, u = bup;
    #pragma unroll 8
    for (int k2 = 0; k2 < 32; ++k2){
      float2 xv = *(const float2*)&xsh[wave][2*k2];
      uint32_t wf = pWf[k2*64 + lane];
      f += xv.x * b2f((u16)wf) + xv.y * b2f((u16)(wf >> 16));
    }
    #pragma unroll 8
    for (int k2 = 32; k2 < 128; ++k2){
      float2 xv = *(const float2*)&xsh[wave][2*k2];
      uint32_t wf = pWf[k2*64 + lane];
      uint32_t wu = pWu[(k2 - 32)*64 + lane];
      f += xv.x * b2f((u16)wf) + xv.y * b2f((u16)(wf >> 16));
      u += xv.x * b2f((u16)wu) + xv.y * b2f((u16)(wu >> 16));
    }
    f = sigmoidf(f);
    u = fmaxf(u, 0.f);
    float wu = fmaxf(f, 0.2f) * aw[t] + (1.f - f) * u;
    out[((size_t)b*4224 + n)*64 + lane] = wu;
    float o = boo;
    #pragma unroll 8
    for (int k2 = 0; k2 < 32; ++k2){
      uint32_t wo2 = pWo[k2*64 + lane];
      o += __shfl(wu, 2*k2, 64) * b2f((u16)wo2) + __shfl(wu, 2*k2 + 1, 64) * b2f((u16)(wo2 >> 16));
    }
    WUo[(size_t)row*64 + lane] = o;
  }
}

// ------------------- K6: word_op from bitOp; 4 waves split n-range; divide by popcount
__global__ __launch_bounds__(256) void k_opagg(
    const u64* __restrict__ bitOp, const float* __restrict__ WUo,
    float* __restrict__ wordop){
  __shared__ int q[4][96];
  __shared__ float sacc[4][64];
  __shared__ int scnt[4];
  int tid = threadIdx.x, lane = tid & 63, wave = tid >> 6;
  int rowIdx = blockIdx.x;                      // b*128 + o
  int b = rowIdx >> 7, o = rowIdx & 127;
  int wrd = o & 1, bit = o >> 1;
  const u64* bp = bitOp + (size_t)b*8192 + (size_t)wave*2048 + wrd;
  u64 lt = (1ULL << lane) - 1ULL;
  u64 vv[16];
  #pragma unroll
  for (int it = 0; it < 16; ++it) vv[it] = bp[(size_t)(it*64 + lane)*2];
  int cnt = 0;
  #pragma unroll
  for (int it = 0; it < 16; ++it){
    bool nz = (vv[it] >> bit) & 1ULL;
    u64 m = __ballot(nz);
    if (nz) q[wave][cnt + (int)__popcll(m & lt)] = wave*1024 + it*64 + lane;
    cnt += (int)__popcll(m);
  }
  const float* Xb = WUo + (size_t)b*4096*64 + lane;
  float acc = 0.f;
  int i = 0;
  for (; i + 8 <= cnt; i += 8){
    int4 c0 = *(const int4*)&q[wave][i];
    int4 c1 = *(const int4*)&q[wave][i + 4];
    float v0 = Xb[(size_t)c0.x*64], v1 = Xb[(size_t)c0.y*64];
    float v2 = Xb[(size_t)c0.z*64], v3 = Xb[(size_t)c0.w*64];
    float v4 = Xb[(size_t)c1.x*64], v5 = Xb[(size_t)c1.y*64];
    float v6 = Xb[(size_t)c1.z*64], v7 = Xb[(size_t)c1.w*64];
    acc += ((v0 + v1) + (v2 + v3)) + ((v4 + v5) + (v6 + v7));
  }
  for (; i < cnt; ++i) acc += Xb[(size_t)q[wave][i]*64];
  sacc[wave][lane] = acc;
  if (lane == 0) scnt[wave] = cnt;
  __syncthreads();
  if (wave == 0){
    float t = sacc[0][lane] + sacc[1][lane] + sacc[2][lane] + sacc[3][lane];
    float deg = (float)(scnt[0] + scnt[1] + scnt[2] + scnt[3]);
    wordop[(size_t)rowIdx*64 + lane] = t / (deg + 1e-30f);
  }
}

// ----------------------------------------------------- K7: op_out epilogue
__global__ __launch_bounds__(256) void k_opout(
    const float* __restrict__ opE, const float* __restrict__ wordop,
    const float* __restrict__ Wf2, const float* __restrict__ bf2,
    const float* __restrict__ Wout, const float* __restrict__ bout,
    float* __restrict__ out){
  __shared__ float sW2[8192];
  __shared__ float sWo[4096];
  __shared__ float xsh[4][128];
  int tid = threadIdx.x;
  for (int i = tid; i < 2048; i += 256) ((float4*)sW2)[i] = ((const float4*)Wf2)[i];
  for (int i = tid; i < 1024; i += 256) ((float4*)sWo)[i] = ((const float4*)Wout)[i];
  __syncthreads();
  int lane = tid & 63, wave = tid >> 6;
  int row = blockIdx.x*4 + wave;
  int b = row >> 7, o = row & 127;
  float e  = opE[(size_t)row*64 + lane];
  float wo = wordop[(size_t)row*64 + lane];
  xsh[wave][lane] = e; xsh[wave][64 + lane] = wo;
  float f = bf2[lane], u = bout[lane];
  #pragma unroll 8
  for (int k = 0; k < 128; ++k) f += xsh[wave][k] * sW2[k*64 + lane];
  #pragma unroll 8
  for (int d = 0; d < 64; ++d)  u += xsh[wave][64 + d] * sWo[d*64 + lane];
  f = sigmoidf(f);
  u = fmaxf(u, 0.f);
  float res = fmaxf(f, 0.2f) * e + (1.f - f) * u;
  out[((size_t)b*4224 + 4096 + o)*64 + lane] = res;
}

extern "C" void kernel_launch(void* const* d_in, const int* in_sizes, int n_in,
                              void* d_out, int out_size, void* d_ws, size_t ws_size,
                              hipStream_t stream){
  const float* w0   = (const float*)d_in[0];
  const float* w1   = (const float*)d_in[1];
  const float* nh   = (const float*)d_in[2];
  const float* opE  = (const float*)d_in[3];
  const float* wes  = (const float*)d_in[4];
  const float* wem  = (const float*)d_in[5];
  const float* wop  = (const float*)d_in[6];
  const float* ww   = (const float*)d_in[7];
  const float* d0   = (const float*)d_in[8];
  const float* d1   = (const float*)d_in[9];
  const float* gw   = (const float*)d_in[10];
  const float* Wg   = (const float*)d_in[11];
  const float* bg   = (const float*)d_in[12];
  const float* Wwk  = (const float*)d_in[13];
  const float* bwk  = (const float*)d_in[14];
  const float* Wws  = (const float*)d_in[15];
  const float* bws  = (const float*)d_in[16];
  const float* Wo   = (const float*)d_in[17];
  const float* bo   = (const float*)d_in[18];
  const float* Wupd = (const float*)d_in[19];
  const float* bupd = (const float*)d_in[20];
  const float* Wf   = (const float*)d_in[21];
  const float* bf   = (const float*)d_in[22];
  const float* Wf2  = (const float*)d_in[23];
  const float* bf2  = (const float*)d_in[24];
  const float* Wout = (const float*)d_in[25];
  const float* bout = (const float*)d_in[26];

  float* ws   = (float*)d_ws;
  float* ghat = ws;                              // 128
  float* Xk   = ws + 128;                        // 524288
  float* Xs   = ws + 524416;                     // 524288
  float* wopm = ws + 1048704;                    // 16384
  u64*  bitBig= (u64*)(ws + 1065088);            // 524288 u64
  u64*  bitD0 = (u64*)(ws + 2113664);            // 131072 u64
  u64*  bitD1 = (u64*)(ws + 2375808);            // 131072 u64
  u64*  bitOp = (u64*)(ws + 2637952);            // 16384 u64
  u16*  wwkn  = (u16*)(ws + 2670720);            // 524288 u16
  u16*  wwsn  = (u16*)(ws + 2932864);            // 524288 u16
  float* WUo  = Xs;                              // Xs dead after k_gath_all
  float* out  = (float*)d_out;

  k_pre<<<1, 128, 0, stream>>>(nh, Wg, bg, ghat);
  k_xform<<<512, 256, 0, stream>>>(w0, w1, Wwk, bwk, Wws, bws, Xk, Xs);
  k_bits_all<<<12288, 256, 0, stream>>>(ww, wem, d0, d1, bitBig, bitD0, bitD1);
  k_bitsop<<<8192, 64, 0, stream>>>(wes, wop, bitOp);
  k_gath_all<<<4096, 256, 0, stream>>>(bitBig, bitD0, bitD1, Xk, Xs, wwkn, wwsn);
  k_update<<<512, 256, 0, stream>>>(w0, w1, gw, ghat, wwkn, wwsn, Wf, bf, Wupd, bupd, Wo, bo, out, WUo);
  k_opagg<<<256, 256, 0, stream>>>(bitOp, WUo, wopm);
  k_opout<<<64, 256, 0, stream>>>(opE, wopm, Wf2, bf2, Wout, bout, out);
}